// Round 1
// baseline (3399.211 us; speedup 1.0000x reference)
//
#include <hip/hip_runtime.h>
#include <math.h>

#define B_   2
#define T_   2048
#define D_   2048
#define H_   16
#define HKV_ 4
#define DH_  128
#define RD_  64
#define KD_  (HKV_ * DH_)   // 512

// =====================================================================
// GEMM: C(M,N) = A(M,K) @ W(N,K)^T   (both row-major, K contiguous)
// 128x128 block, BK=16, 256 threads, 8x8 micro-tile (interleaved map)
// =====================================================================
#define GBM 128
#define GBN 128
#define GBK 16
#define GSTR 20   // LDS row stride in floats (80 B, float4-aligned, odd*4)

__global__ __launch_bounds__(256) void gemm_nt(const float* __restrict__ A,
                                               const float* __restrict__ W,
                                               float* __restrict__ C,
                                               int M, int N, int K) {
  __shared__ float As[GBM][GSTR];
  __shared__ float Bs[GBN][GSTR];
  const int tid = threadIdx.x;
  const int ti = tid >> 4;   // 0..15
  const int tj = tid & 15;   // 0..15
  const int bm = blockIdx.y * GBM;
  const int bn = blockIdx.x * GBN;

  float acc[8][8];
#pragma unroll
  for (int i = 0; i < 8; i++)
#pragma unroll
    for (int j = 0; j < 8; j++) acc[i][j] = 0.0f;

  for (int k0 = 0; k0 < K; k0 += GBK) {
    // stage 128x16 tiles of A and W: 2 float4 per thread each
#pragma unroll
    for (int e = 0; e < 2; e++) {
      int idx4 = tid + e * 256;          // 0..511 (4 float4 per row)
      int r = idx4 >> 2;
      int c4 = (idx4 & 3) << 2;
      float4 av = *(const float4*)(A + (size_t)(bm + r) * K + k0 + c4);
      float4 wv = *(const float4*)(W + (size_t)(bn + r) * K + k0 + c4);
      *(float4*)&As[r][c4] = av;
      *(float4*)&Bs[r][c4] = wv;
    }
    __syncthreads();
#pragma unroll
    for (int kk = 0; kk < GBK; kk += 4) {
      float4 a4[8], b4[8];
#pragma unroll
      for (int i = 0; i < 8; i++) a4[i] = *(const float4*)&As[ti + 16 * i][kk];
#pragma unroll
      for (int j = 0; j < 8; j++) b4[j] = *(const float4*)&Bs[tj + 16 * j][kk];
#pragma unroll
      for (int i = 0; i < 8; i++)
#pragma unroll
        for (int j = 0; j < 8; j++)
          acc[i][j] += a4[i].x * b4[j].x + a4[i].y * b4[j].y +
                       a4[i].z * b4[j].z + a4[i].w * b4[j].w;
    }
    __syncthreads();
  }
#pragma unroll
  for (int i = 0; i < 8; i++)
#pragma unroll
    for (int j = 0; j < 8; j++)
      C[(size_t)(bm + ti + 16 * i) * N + (bn + tj + 16 * j)] = acc[i][j];
}

// =====================================================================
// RoPE (interleaved pairs on first RD dims) + optional temp[h] scale.
// One 64-lane unit per (b,t,head). scale applies to ALL DH dims.
// =====================================================================
__global__ __launch_bounds__(256) void rope_scale(float* __restrict__ qk,
                                                  const float* __restrict__ cosT,
                                                  const float* __restrict__ sinT,
                                                  const float* __restrict__ temp,
                                                  int nheads, float extra_scale,
                                                  int use_temp) {
  const int unit = blockIdx.x * 4 + (threadIdx.x >> 6);
  const int lane = threadIdx.x & 63;
  const int h = unit % nheads;
  const int bt = unit / nheads;
  const int t = bt & (T_ - 1);
  const float scale = extra_scale * (use_temp ? temp[h] : 1.0f);
  float* p = qk + (size_t)bt * (nheads * DH_) + h * DH_;
  if (lane < 32) {
    const int i = lane;
    float x1 = p[2 * i], x2 = p[2 * i + 1];
    float c = cosT[t * (RD_ / 2) + i];
    float s = sinT[t * (RD_ / 2) + i];
    p[2 * i]     = (x1 * c - x2 * s) * scale;
    p[2 * i + 1] = (x1 * s + x2 * c) * scale;
  } else {
    const int d0 = RD_ + (lane - 32) * 2;
    p[d0]     *= scale;
    p[d0 + 1] *= scale;
  }
}

// =====================================================================
// Causal GQA flash attention, fp32.
// Block = (b, h, 64-row q tile); 32-wide K/V tiles; online softmax.
// q layout (B*T, H*DH); k/v layout (B*T, HKV*DH); ao layout (B*T, H*DH)
// =====================================================================
#define FBQ 64
#define FBK 32
#define QSTR 132   // 128 + 4 pad (float4-aligned, bank stride 4)
#define SSTR 33    // 32 + 1 pad (odd -> conflict-free row scans)

__global__ __launch_bounds__(256) void flash_attn(const float* __restrict__ q,
                                                  const float* __restrict__ kkv,
                                                  const float* __restrict__ vkv,
                                                  float* __restrict__ ao) {
  __shared__ float Qs[FBQ][QSTR];
  __shared__ float Ks[FBK][QSTR];
  __shared__ float Vs[FBK][QSTR];
  __shared__ float Ss[FBQ][SSTR];
  __shared__ float m_s[FBQ], l_s[FBQ], al_s[FBQ];
  __shared__ float pmax[4][FBQ], psum[4][FBQ];

  const int numQT = T_ / FBQ;  // 32
  const int bid = blockIdx.x;
  const int qt = bid % numQT;
  const int bh = bid / numQT;
  const int h = bh % H_;
  const int b = bh / H_;
  const int kvh = h / (H_ / HKV_);

  const int tid = threadIdx.x;
  const int ti = tid >> 4;  // 0..15
  const int tj = tid & 15;  // 0..15

  // load Q tile (64 x 128), 8 float4 per thread, coalesced
  {
    const float* qb = q + (size_t)(b * T_ + qt * FBQ) * D_ + h * DH_;
#pragma unroll
    for (int e = 0; e < 8; e++) {
      int idx4 = tid + e * 256;       // 0..2047 (32 float4 per row)
      int r = idx4 >> 5;
      int c = (idx4 & 31) << 2;
      *(float4*)&Qs[r][c] = *(const float4*)(qb + (size_t)r * D_ + c);
    }
  }
  if (tid < FBQ) { m_s[tid] = -1e30f; l_s[tid] = 0.0f; }

  float o[4][8];
#pragma unroll
  for (int i = 0; i < 4; i++)
#pragma unroll
    for (int j = 0; j < 8; j++) o[i][j] = 0.0f;

  __syncthreads();

  const int qg = qt * FBQ;
  const int ktEnd = (qg + FBQ + FBK - 1) / FBK;  // 2*qt + 2
  for (int kt = 0; kt < ktEnd; kt++) {
    const float* kb = kkv + (size_t)(b * T_ + kt * FBK) * KD_ + kvh * DH_;
    const float* vb = vkv + (size_t)(b * T_ + kt * FBK) * KD_ + kvh * DH_;
#pragma unroll
    for (int e = 0; e < 4; e++) {
      int idx4 = tid + e * 256;       // 0..1023
      int r = idx4 >> 5;
      int c = (idx4 & 31) << 2;
      *(float4*)&Ks[r][c] = *(const float4*)(kb + (size_t)r * KD_ + c);
      *(float4*)&Vs[r][c] = *(const float4*)(vb + (size_t)r * KD_ + c);
    }
    __syncthreads();

    // ---- S = Q @ K^T : rows ti+16i (x4), cols tj+16j (x2) ----
    float s[4][2];
#pragma unroll
    for (int i = 0; i < 4; i++) { s[i][0] = 0.0f; s[i][1] = 0.0f; }
    for (int kk = 0; kk < DH_; kk += 4) {
      float4 a4[4], b4[2];
#pragma unroll
      for (int i = 0; i < 4; i++) a4[i] = *(const float4*)&Qs[ti + 16 * i][kk];
#pragma unroll
      for (int j = 0; j < 2; j++) b4[j] = *(const float4*)&Ks[tj + 16 * j][kk];
#pragma unroll
      for (int i = 0; i < 4; i++)
#pragma unroll
        for (int j = 0; j < 2; j++)
          s[i][j] += a4[i].x * b4[j].x + a4[i].y * b4[j].y +
                     a4[i].z * b4[j].z + a4[i].w * b4[j].w;
    }
    const int kg = kt * FBK;
#pragma unroll
    for (int i = 0; i < 4; i++)
#pragma unroll
      for (int j = 0; j < 2; j++) {
        int r = ti + 16 * i, c = tj + 16 * j;
        float val = s[i][j];
        if (kg + c > qg + r) val = -1e30f;  // causal mask
        Ss[r][c] = val;
      }
    __syncthreads();

    // ---- online softmax over this 32-col slab ----
    {
      const int row = tid & 63, part = tid >> 6;
      const int c0 = part * 8;
      float mx = -1e30f;
#pragma unroll
      for (int c = 0; c < 8; c++) mx = fmaxf(mx, Ss[row][c0 + c]);
      pmax[part][row] = mx;
    }
    __syncthreads();
    if (tid < FBQ) {
      float mold = m_s[tid];
      float mnew = fmaxf(fmaxf(pmax[0][tid], pmax[1][tid]),
                         fmaxf(pmax[2][tid], pmax[3][tid]));
      mnew = fmaxf(mnew, mold);
      al_s[tid] = __expf(mold - mnew);
      m_s[tid] = mnew;
    }
    __syncthreads();
    {
      const int row = tid & 63, part = tid >> 6;
      const int c0 = part * 8;
      const float mrow = m_s[row];
      float sm = 0.0f;
#pragma unroll
      for (int c = 0; c < 8; c++) {
        float pv = __expf(Ss[row][c0 + c] - mrow);
        Ss[row][c0 + c] = pv;
        sm += pv;
      }
      psum[part][row] = sm;
    }
    __syncthreads();
    if (tid < FBQ) {
      l_s[tid] = l_s[tid] * al_s[tid] +
                 psum[0][tid] + psum[1][tid] + psum[2][tid] + psum[3][tid];
    }

    // ---- O = O*alpha + P @ V : rows ti+16i, cols {tj*4.., 64+tj*4..} ----
    float al[4];
#pragma unroll
    for (int i = 0; i < 4; i++) al[i] = al_s[ti + 16 * i];
#pragma unroll
    for (int i = 0; i < 4; i++)
#pragma unroll
      for (int j = 0; j < 8; j++) o[i][j] *= al[i];
    for (int c = 0; c < FBK; c++) {
      float p_[4];
#pragma unroll
      for (int i = 0; i < 4; i++) p_[i] = Ss[ti + 16 * i][c];
      float4 va  = *(const float4*)&Vs[c][tj * 4];
      float4 vb2 = *(const float4*)&Vs[c][64 + tj * 4];
#pragma unroll
      for (int i = 0; i < 4; i++) {
        o[i][0] += p_[i] * va.x;  o[i][1] += p_[i] * va.y;
        o[i][2] += p_[i] * va.z;  o[i][3] += p_[i] * va.w;
        o[i][4] += p_[i] * vb2.x; o[i][5] += p_[i] * vb2.y;
        o[i][6] += p_[i] * vb2.z; o[i][7] += p_[i] * vb2.w;
      }
    }
    __syncthreads();  // protect Ks/Vs/Ss before next slab
  }

  // ---- epilogue: O / l, store to (B*T, H*DH) ----
  float* ab = ao + (size_t)(b * T_ + qg) * D_ + h * DH_;
#pragma unroll
  for (int i = 0; i < 4; i++) {
    const int r = ti + 16 * i;
    const float inv = 1.0f / l_s[r];
    float4 o1, o2;
    o1.x = o[i][0] * inv; o1.y = o[i][1] * inv;
    o1.z = o[i][2] * inv; o1.w = o[i][3] * inv;
    o2.x = o[i][4] * inv; o2.y = o[i][5] * inv;
    o2.z = o[i][6] * inv; o2.w = o[i][7] * inv;
    *(float4*)(ab + (size_t)r * D_ + tj * 4)      = o1;
    *(float4*)(ab + (size_t)r * D_ + 64 + tj * 4) = o2;
  }
}

// =====================================================================
// Launch
// =====================================================================
extern "C" void kernel_launch(void* const* d_in, const int* in_sizes, int n_in,
                              void* d_out, int out_size, void* d_ws, size_t ws_size,
                              hipStream_t stream) {
  const float* x    = (const float*)d_in[0];
  const float* cosT = (const float*)d_in[1];
  const float* sinT = (const float*)d_in[2];
  const float* Wq   = (const float*)d_in[3];
  const float* Wk   = (const float*)d_in[4];
  const float* Wv   = (const float*)d_in[5];
  const float* Wo   = (const float*)d_in[6];
  const float* temp = (const float*)d_in[7];
  float* out = (float*)d_out;

  float* ws = (float*)d_ws;
  const size_t QN = (size_t)B_ * T_ * D_;   // 8388608
  const size_t KN = (size_t)B_ * T_ * KD_;  // 2097152
  float* qb  = ws;                 // q  (B*T, H*DH)
  float* kb  = ws + QN;            // k  (B*T, HKV*DH)
  float* vb  = ws + QN + KN;       // v
  float* aob = ws + QN + 2 * KN;   // attention output (B*T, H*DH)

  const int M = B_ * T_;  // 4096
  dim3 blk(256);

  // projections
  gemm_nt<<<dim3(D_ / GBN, M / GBM), blk, 0, stream>>>(x, Wq, qb, M, D_, D_);
  gemm_nt<<<dim3(KD_ / GBN, M / GBM), blk, 0, stream>>>(x, Wk, kb, M, KD_, D_);
  gemm_nt<<<dim3(KD_ / GBN, M / GBM), blk, 0, stream>>>(x, Wv, vb, M, KD_, D_);

  // rope: fold temp[h] and the scores' 1/sqrt(DH) into q
  const float inv_sqrt_dh = 1.0f / sqrtf((float)DH_);
  rope_scale<<<(M * H_) / 4, blk, 0, stream>>>(qb, cosT, sinT, temp, H_,
                                               inv_sqrt_dh, 1);
  rope_scale<<<(M * HKV_) / 4, blk, 0, stream>>>(kb, cosT, sinT, temp, HKV_,
                                                 1.0f, 0);

  // causal GQA attention
  flash_attn<<<B_ * H_ * (T_ / FBQ), blk, 0, stream>>>(qb, kb, vb, aob);

  // output projection
  gemm_nt<<<dim3(D_ / GBN, M / GBM), blk, 0, stream>>>(aob, Wo, out, M, D_, D_);
}

// Round 2
// 586.906 us; speedup vs baseline: 5.7918x; 5.7918x over previous
//
#include <hip/hip_runtime.h>
#include <hip/hip_bf16.h>
#include <math.h>

#define B_   2
#define T_   2048
#define D_   2048
#define H_   16
#define HKV_ 4
#define DH_  128
#define RD_  64
#define KD_  (HKV_ * DH_)   // 512

typedef __attribute__((ext_vector_type(8))) short  short8;   // 8 x bf16 (4 VGPRs)
typedef __attribute__((ext_vector_type(4))) float  floatx4;  // MFMA C/D

// async global->LDS, 16B per lane; lds base must be wave-uniform
__device__ __forceinline__ void async16(const __hip_bfloat16* g, __hip_bfloat16* l) {
  __builtin_amdgcn_global_load_lds(
      (const __attribute__((address_space(1))) void*)g,
      (__attribute__((address_space(3))) void*)l, 16, 0, 0);
}

// =====================================================================
// fused fp32 -> bf16 conversion for x, Wq, Wk, Wv, Wo
// =====================================================================
struct ConvArgs {
  const float* src[5];
  __hip_bfloat16* dst[5];
  int n[5];
};

__global__ __launch_bounds__(256) void conv_bf16(ConvArgs a) {
  const int arr = blockIdx.y;
  const int i = (blockIdx.x * 256 + threadIdx.x) * 8;
  if (i >= a.n[arr]) return;
  const float4 f1 = *(const float4*)(a.src[arr] + i);
  const float4 f2 = *(const float4*)(a.src[arr] + i + 4);
  union { short8 v; __hip_bfloat16 h[8]; } o;
  o.h[0] = __float2bfloat16(f1.x); o.h[1] = __float2bfloat16(f1.y);
  o.h[2] = __float2bfloat16(f1.z); o.h[3] = __float2bfloat16(f1.w);
  o.h[4] = __float2bfloat16(f2.x); o.h[5] = __float2bfloat16(f2.y);
  o.h[6] = __float2bfloat16(f2.z); o.h[7] = __float2bfloat16(f2.w);
  *(short8*)(a.dst[arr] + i) = o.v;
}

// =====================================================================
// bf16 MFMA GEMM: C(M,N) = A(M,K) @ B(N,K)^T, both row-major K-contig.
// 128x128 tile, BK=32, 4 waves (2x2), 4x4 16x16x32 frags per wave.
// LDS unit layout: unit = panel*64 + kc*16 + rlow  (8 bf16 per unit)
//   -> staging: issue I covers panel I, lanes = kc(2b)*16 + rlow(4b):
//      coalesced 16 rows x 64B; frag read bank = m16*4 -> 2-way (free).
// =====================================================================
template <int OUT_BF16>
__global__ __launch_bounds__(256) void gemm_bt_mfma(const __hip_bfloat16* __restrict__ A,
                                                    const __hip_bfloat16* __restrict__ Bw,
                                                    void* __restrict__ Cout,
                                                    int M, int N, int K) {
  __shared__ __hip_bfloat16 As[128 * 32];
  __shared__ __hip_bfloat16 Bs[128 * 32];
  const int tid = threadIdx.x;
  const int lane = tid & 63;
  const int w = tid >> 6;
  const int wm = w >> 1, wn = w & 1;
  const int quad = lane >> 4, m16 = lane & 15;
  const int bm = blockIdx.y * 128, bn = blockIdx.x * 128;

  floatx4 acc[4][4] = {};

  const int kcL = lane >> 4;      // staging kc (0..3)
  const int rlL = lane & 15;      // staging row-low

  for (int k0 = 0; k0 < K; k0 += 32) {
#pragma unroll
    for (int e = 0; e < 2; e++) {
      const int p = w * 2 + e;    // panel 0..7
      const __hip_bfloat16* ga = A  + (size_t)(bm + p * 16 + rlL) * K + k0 + kcL * 8;
      const __hip_bfloat16* gb = Bw + (size_t)(bn + p * 16 + rlL) * K + k0 + kcL * 8;
      async16(ga, &As[p * 512]);
      async16(gb, &Bs[p * 512]);
    }
    __syncthreads();

    short8 a[4], b[4];
#pragma unroll
    for (int mi = 0; mi < 4; mi++) {
      const int unit = (wm * 4 + mi) * 64 + quad * 16 + m16;
      a[mi] = *(const short8*)&As[unit * 8];
    }
#pragma unroll
    for (int ni = 0; ni < 4; ni++) {
      const int unit = (wn * 4 + ni) * 64 + quad * 16 + m16;
      b[ni] = *(const short8*)&Bs[unit * 8];
    }
#pragma unroll
    for (int mi = 0; mi < 4; mi++)
#pragma unroll
      for (int ni = 0; ni < 4; ni++)
        acc[mi][ni] = __builtin_amdgcn_mfma_f32_16x16x32_bf16(a[mi], b[ni], acc[mi][ni], 0, 0, 0);
    __syncthreads();
  }

#pragma unroll
  for (int mi = 0; mi < 4; mi++)
#pragma unroll
    for (int ni = 0; ni < 4; ni++)
#pragma unroll
      for (int reg = 0; reg < 4; reg++) {
        const int row = bm + wm * 64 + mi * 16 + quad * 4 + reg;
        const int col = bn + wn * 64 + ni * 16 + m16;
        if (OUT_BF16)
          ((__hip_bfloat16*)Cout)[(size_t)row * N + col] = __float2bfloat16(acc[mi][ni][reg]);
        else
          ((float*)Cout)[(size_t)row * N + col] = acc[mi][ni][reg];
      }
}

// =====================================================================
// RoPE on bf16 (interleaved pairs over first RD dims) + scale all dims.
// =====================================================================
__global__ __launch_bounds__(256) void rope_bf16(__hip_bfloat16* __restrict__ qk,
                                                 const float* __restrict__ cosT,
                                                 const float* __restrict__ sinT,
                                                 const float* __restrict__ temp,
                                                 int nheads, float extra, int use_temp) {
  const int unit = blockIdx.x * 4 + (threadIdx.x >> 6);
  const int lane = threadIdx.x & 63;
  const int h = unit % nheads;
  const int bt = unit / nheads;
  const int t = bt & (T_ - 1);
  const float scale = extra * (use_temp ? temp[h] : 1.0f);
  __hip_bfloat16* p = qk + (size_t)bt * (nheads * DH_) + h * DH_;
  if (lane < 32) {
    const float x1 = __bfloat162float(p[2 * lane]);
    const float x2 = __bfloat162float(p[2 * lane + 1]);
    const float c = cosT[t * (RD_ / 2) + lane];
    const float s = sinT[t * (RD_ / 2) + lane];
    p[2 * lane]     = __float2bfloat16((x1 * c - x2 * s) * scale);
    p[2 * lane + 1] = __float2bfloat16((x1 * s + x2 * c) * scale);
  } else {
    const int d0 = RD_ + (lane - 32) * 2;
    p[d0]     = __float2bfloat16(__bfloat162float(p[d0]) * scale);
    p[d0 + 1] = __float2bfloat16(__bfloat162float(p[d0 + 1]) * scale);
  }
}

// =====================================================================
// V transpose: v (B*T, KD) -> vt (B, HKV, DH, T)
// 64x64 tiles through LDS.
// =====================================================================
__global__ __launch_bounds__(256) void transpose_v(const __hip_bfloat16* __restrict__ v,
                                                   __hip_bfloat16* __restrict__ vt) {
  __shared__ __hip_bfloat16 Ts[64][72];
  const int t0 = blockIdx.x * 64, d0 = blockIdx.y * 64;
  const int bh = blockIdx.z;
  const int b = bh >> 2, hv = bh & 3;
  const int tid = threadIdx.x;
  const int r = tid >> 2, c0 = (tid & 3) * 16;

  const __hip_bfloat16* src = v + ((size_t)(b * T_) + t0 + r) * KD_ + hv * DH_ + d0 + c0;
  *(short8*)&Ts[r][c0]     = *(const short8*)(src);
  *(short8*)&Ts[r][c0 + 8] = *(const short8*)(src + 8);
  __syncthreads();

  union { short8 v8[2]; __hip_bfloat16 h[16]; } tmp;
#pragma unroll
  for (int j = 0; j < 16; j++) tmp.h[j] = Ts[c0 + j][r];
  __hip_bfloat16* dst = vt + ((size_t)((b * HKV_ + hv) * DH_) + d0 + r) * T_ + t0 + c0;
  *(short8*)dst       = tmp.v8[0];
  *(short8*)(dst + 8) = tmp.v8[1];
}

// =====================================================================
// MFMA flash attention (causal, GQA).
// Block = 4 waves; wave w owns 16 q-rows. 64-wide K slabs.
// q (B*T, H*DH) bf16 (roped+scaled), k (B*T, KD) bf16 (roped),
// vt (B, HKV, DH, T) bf16, ao (B*T, H*DH) bf16.
// =====================================================================
__global__ __launch_bounds__(256) void flash_attn_mfma(
    const __hip_bfloat16* __restrict__ q, const __hip_bfloat16* __restrict__ k,
    const __hip_bfloat16* __restrict__ vt, __hip_bfloat16* __restrict__ ao) {
  // Ks: 4 panels(16 k-rows) x 16 kc -> unit = panel*256 + kc*16 + rlow
  // Vs: 8 panels(16 dh)     x  8 tc -> unit = panel*128 + tc*16 + rlow
  __shared__ __hip_bfloat16 Ks[1024 * 8];
  __shared__ __hip_bfloat16 Vs[1024 * 8];
  __shared__ __hip_bfloat16 Pl[4][16][72];

  const int tid = threadIdx.x, lane = tid & 63, w = tid >> 6;
  const int quad = lane >> 4, m16 = lane & 15;
  const int bid = blockIdx.x;
  const int qt = bid & 31;
  const int h = (bid >> 5) & 15;
  const int b = bid >> 9;
  const int kvh = h >> 2;
  const int qg = qt * 64;

  // Q fragments in registers (4 dh-steps of 32)
  short8 qa[4];
  {
    const __hip_bfloat16* qp = q + ((size_t)(b * T_) + qg + w * 16 + m16) * D_ + h * DH_;
#pragma unroll
    for (int ks = 0; ks < 4; ks++) qa[ks] = *(const short8*)(qp + ks * 32 + quad * 8);
  }

  floatx4 o_acc[8] = {};
  float m_i[4], l_i[4];
#pragma unroll
  for (int r = 0; r < 4; r++) { m_i[r] = -1e30f; l_i[r] = 0.0f; }

  const int subq = lane >> 4;   // staging sub-chunk
  const int rlow = lane & 15;

  for (int kt = 0; kt <= qt; kt++) {
    // ---- stage K (16 issues) + Vt (16 issues), 4 each per wave ----
#pragma unroll
    for (int e = 0; e < 4; e++) {
      const int I = w * 4 + e;
      {
        const int panel = I >> 2, kc = (I & 3) * 4 + subq;
        const __hip_bfloat16* g =
            k + ((size_t)(b * T_) + kt * 64 + panel * 16 + rlow) * KD_ + kvh * DH_ + kc * 8;
        async16(g, &Ks[I * 512]);
      }
      {
        const int panel = I >> 1, tc = (I & 1) * 4 + subq;
        const __hip_bfloat16* g =
            vt + ((size_t)(b * HKV_ + kvh) * DH_ + panel * 16 + rlow) * T_ + kt * 64 + tc * 8;
        async16(g, &Vs[I * 512]);
      }
    }
    __syncthreads();

    // ---- S = Q K^T (16 q-rows x 64 k-cols per wave) ----
    floatx4 sacc[4] = {};
#pragma unroll
    for (int ni = 0; ni < 4; ni++)
#pragma unroll
      for (int ks = 0; ks < 4; ks++) {
        const int unit = ni * 256 + (ks * 4 + quad) * 16 + m16;
        const short8 kb = *(const short8*)&Ks[unit * 8];
        sacc[ni] = __builtin_amdgcn_mfma_f32_16x16x32_bf16(qa[ks], kb, sacc[ni], 0, 0, 0);
      }

    if (kt == qt) {  // causal mask (only the diagonal slab has masked cols)
#pragma unroll
      for (int ni = 0; ni < 4; ni++) {
        const int colg = kt * 64 + ni * 16 + m16;
#pragma unroll
        for (int reg = 0; reg < 4; reg++) {
          const int rowg = qg + w * 16 + quad * 4 + reg;
          if (colg > rowg) sacc[ni][reg] = -1e30f;
        }
      }
    }

    // ---- online softmax (rows are wave-private; reduce over 16 lanes) ----
    float alpha[4];
#pragma unroll
    for (int reg = 0; reg < 4; reg++) {
      float v = fmaxf(fmaxf(sacc[0][reg], sacc[1][reg]), fmaxf(sacc[2][reg], sacc[3][reg]));
      v = fmaxf(v, __shfl_xor(v, 1));
      v = fmaxf(v, __shfl_xor(v, 2));
      v = fmaxf(v, __shfl_xor(v, 4));
      v = fmaxf(v, __shfl_xor(v, 8));
      const float mn = fmaxf(m_i[reg], v);
      alpha[reg] = __expf(m_i[reg] - mn);
      m_i[reg] = mn;
    }
#pragma unroll
    for (int ni = 0; ni < 4; ni++)
#pragma unroll
      for (int reg = 0; reg < 4; reg++)
        sacc[ni][reg] = __expf(sacc[ni][reg] - m_i[reg]);
#pragma unroll
    for (int reg = 0; reg < 4; reg++) {
      float s = sacc[0][reg] + sacc[1][reg] + sacc[2][reg] + sacc[3][reg];
      s += __shfl_xor(s, 1);
      s += __shfl_xor(s, 2);
      s += __shfl_xor(s, 4);
      s += __shfl_xor(s, 8);
      l_i[reg] = l_i[reg] * alpha[reg] + s;
    }

    // ---- P -> LDS (C-layout write, A-layout read), rescale O ----
#pragma unroll
    for (int ni = 0; ni < 4; ni++)
#pragma unroll
      for (int reg = 0; reg < 4; reg++)
        Pl[w][quad * 4 + reg][ni * 16 + m16] = __float2bfloat16(sacc[ni][reg]);
#pragma unroll
    for (int ni = 0; ni < 8; ni++)
#pragma unroll
      for (int reg = 0; reg < 4; reg++) o_acc[ni][reg] *= alpha[reg];

    // ---- O += P V ----
#pragma unroll
    for (int ks2 = 0; ks2 < 2; ks2++) {
      const short8 pa = *(const short8*)&Pl[w][m16][ks2 * 32 + quad * 8];
#pragma unroll
      for (int ni = 0; ni < 8; ni++) {
        const int unit = ni * 128 + (ks2 * 4 + quad) * 16 + m16;
        const short8 vb = *(const short8*)&Vs[unit * 8];
        o_acc[ni] = __builtin_amdgcn_mfma_f32_16x16x32_bf16(pa, vb, o_acc[ni], 0, 0, 0);
      }
    }
    __syncthreads();
  }

  // ---- epilogue ----
  const size_t orow = (size_t)(b * T_) + qg + w * 16;
#pragma unroll
  for (int reg = 0; reg < 4; reg++) {
    const float inv = 1.0f / l_i[reg];
#pragma unroll
    for (int ni = 0; ni < 8; ni++)
      ao[(orow + quad * 4 + reg) * D_ + h * DH_ + ni * 16 + m16] =
          __float2bfloat16(o_acc[ni][reg] * inv);
  }
}

// =====================================================================
// Launch
// =====================================================================
extern "C" void kernel_launch(void* const* d_in, const int* in_sizes, int n_in,
                              void* d_out, int out_size, void* d_ws, size_t ws_size,
                              hipStream_t stream) {
  const float* x    = (const float*)d_in[0];
  const float* cosT = (const float*)d_in[1];
  const float* sinT = (const float*)d_in[2];
  const float* Wq   = (const float*)d_in[3];
  const float* Wk   = (const float*)d_in[4];
  const float* Wv   = (const float*)d_in[5];
  const float* Wo   = (const float*)d_in[6];
  const float* temp = (const float*)d_in[7];
  float* out = (float*)d_out;

  const int M = B_ * T_;                    // 4096
  const size_t XN = (size_t)M * D_;         // 8388608
  const size_t WQN = (size_t)D_ * D_;       // 4194304
  const size_t WKN = (size_t)KD_ * D_;      // 1048576
  const size_t KN = (size_t)M * KD_;        // 2097152

  __hip_bfloat16* ws = (__hip_bfloat16*)d_ws;
  __hip_bfloat16* xb  = ws;                 ws += XN;
  __hip_bfloat16* wqb = ws;                 ws += WQN;
  __hip_bfloat16* wkb = ws;                 ws += WKN;
  __hip_bfloat16* wvb = ws;                 ws += WKN;
  __hip_bfloat16* wob = ws;                 ws += WQN;
  __hip_bfloat16* qb  = ws;                 ws += XN;
  __hip_bfloat16* kb  = ws;                 ws += KN;
  __hip_bfloat16* vb  = ws;                 ws += KN;
  __hip_bfloat16* vtb = ws;                 ws += KN;
  __hip_bfloat16* aob = ws;                 ws += XN;

  dim3 blk(256);

  // 1. convert inputs to bf16
  ConvArgs ca;
  ca.src[0] = x;  ca.dst[0] = xb;  ca.n[0] = (int)XN;
  ca.src[1] = Wq; ca.dst[1] = wqb; ca.n[1] = (int)WQN;
  ca.src[2] = Wk; ca.dst[2] = wkb; ca.n[2] = (int)WKN;
  ca.src[3] = Wv; ca.dst[3] = wvb; ca.n[3] = (int)WKN;
  ca.src[4] = Wo; ca.dst[4] = wob; ca.n[4] = (int)WQN;
  conv_bf16<<<dim3(4096, 5), blk, 0, stream>>>(ca);

  // 2. projections (bf16 out)
  gemm_bt_mfma<1><<<dim3(D_ / 128, M / 128), blk, 0, stream>>>(xb, wqb, qb, M, D_, D_);
  gemm_bt_mfma<1><<<dim3(KD_ / 128, M / 128), blk, 0, stream>>>(xb, wkb, kb, M, KD_, D_);
  gemm_bt_mfma<1><<<dim3(KD_ / 128, M / 128), blk, 0, stream>>>(xb, wvb, vb, M, KD_, D_);

  // 3. rope (+ temp & 1/sqrt(DH) folded into q)
  const float inv_sqrt_dh = 1.0f / sqrtf((float)DH_);
  rope_bf16<<<(M * H_) / 4, blk, 0, stream>>>(qb, cosT, sinT, temp, H_, inv_sqrt_dh, 1);
  rope_bf16<<<(M * HKV_) / 4, blk, 0, stream>>>(kb, cosT, sinT, temp, HKV_, 1.0f, 0);

  // 4. transpose V for PV b-fragments
  transpose_v<<<dim3(T_ / 64, DH_ / 64, B_ * HKV_), blk, 0, stream>>>(vb, vtb);

  // 5. attention
  flash_attn_mfma<<<B_ * H_ * (T_ / 64), blk, 0, stream>>>(qb, kb, vtb, aob);

  // 6. output projection (fp32 out)
  gemm_bt_mfma<0><<<dim3(D_ / 128, M / 128), blk, 0, stream>>>(aob, wob, out, M, D_, D_);
}

// Round 3
// 474.803 us; speedup vs baseline: 7.1592x; 1.2361x over previous
//
#include <hip/hip_runtime.h>
#include <hip/hip_bf16.h>
#include <math.h>

#define B_   2
#define T_   2048
#define D_   2048
#define H_   16
#define HKV_ 4
#define DH_  128
#define RD_  64
#define KD_  (HKV_ * DH_)   // 512
#define SQKV 3072           // fused qkv row stride (H*DH + 2*HKV*DH)

typedef __attribute__((ext_vector_type(8))) short  short8;   // 8 x bf16 (4 VGPRs)
typedef __attribute__((ext_vector_type(4))) float  floatx4;  // MFMA C/D

// async global->LDS, 16B per lane; lds base must be wave-uniform
__device__ __forceinline__ void async16(const __hip_bfloat16* g, __hip_bfloat16* l) {
  __builtin_amdgcn_global_load_lds(
      (const __attribute__((address_space(1))) void*)g,
      (__attribute__((address_space(3))) void*)l, 16, 0, 0);
}

// =====================================================================
// fused fp32 -> bf16 conversion for x, Wq, Wk, Wv, Wo
// =====================================================================
struct ConvArgs {
  const float* src[5];
  __hip_bfloat16* dst[5];
  int n[5];
};

__global__ __launch_bounds__(256) void conv_bf16(ConvArgs a) {
  const int arr = blockIdx.y;
  const int i = (blockIdx.x * 256 + threadIdx.x) * 8;
  if (i >= a.n[arr]) return;
  const float4 f1 = *(const float4*)(a.src[arr] + i);
  const float4 f2 = *(const float4*)(a.src[arr] + i + 4);
  union { short8 v; __hip_bfloat16 h[8]; } o;
  o.h[0] = __float2bfloat16(f1.x); o.h[1] = __float2bfloat16(f1.y);
  o.h[2] = __float2bfloat16(f1.z); o.h[3] = __float2bfloat16(f1.w);
  o.h[4] = __float2bfloat16(f2.x); o.h[5] = __float2bfloat16(f2.y);
  o.h[6] = __float2bfloat16(f2.z); o.h[7] = __float2bfloat16(f2.w);
  *(short8*)(a.dst[arr] + i) = o.v;
}

// =====================================================================
// bf16 MFMA GEMM: C(M,N) = A(M,K) @ B(N,K)^T  (m97-style, unchanged)
// =====================================================================
template <int OUT_BF16>
__global__ __launch_bounds__(256) void gemm_bt_mfma(const __hip_bfloat16* __restrict__ A,
                                                    const __hip_bfloat16* __restrict__ Bw,
                                                    void* __restrict__ Cout,
                                                    int M, int N, int K) {
  __shared__ __hip_bfloat16 As[128 * 32];
  __shared__ __hip_bfloat16 Bs[128 * 32];
  const int tid = threadIdx.x;
  const int lane = tid & 63;
  const int w = tid >> 6;
  const int wm = w >> 1, wn = w & 1;
  const int quad = lane >> 4, m16 = lane & 15;
  const int bm = blockIdx.y * 128, bn = blockIdx.x * 128;

  floatx4 acc[4][4] = {};

  const int kcL = lane >> 4;
  const int rlL = lane & 15;

  for (int k0 = 0; k0 < K; k0 += 32) {
#pragma unroll
    for (int e = 0; e < 2; e++) {
      const int p = w * 2 + e;
      const __hip_bfloat16* ga = A  + (size_t)(bm + p * 16 + rlL) * K + k0 + kcL * 8;
      const __hip_bfloat16* gb = Bw + (size_t)(bn + p * 16 + rlL) * K + k0 + kcL * 8;
      async16(ga, &As[p * 512]);
      async16(gb, &Bs[p * 512]);
    }
    __syncthreads();

    short8 a[4], b[4];
#pragma unroll
    for (int mi = 0; mi < 4; mi++) {
      const int unit = (wm * 4 + mi) * 64 + quad * 16 + m16;
      a[mi] = *(const short8*)&As[unit * 8];
    }
#pragma unroll
    for (int ni = 0; ni < 4; ni++) {
      const int unit = (wn * 4 + ni) * 64 + quad * 16 + m16;
      b[ni] = *(const short8*)&Bs[unit * 8];
    }
#pragma unroll
    for (int mi = 0; mi < 4; mi++)
#pragma unroll
      for (int ni = 0; ni < 4; ni++)
        acc[mi][ni] = __builtin_amdgcn_mfma_f32_16x16x32_bf16(a[mi], b[ni], acc[mi][ni], 0, 0, 0);
    __syncthreads();
  }

#pragma unroll
  for (int mi = 0; mi < 4; mi++)
#pragma unroll
    for (int ni = 0; ni < 4; ni++)
#pragma unroll
      for (int reg = 0; reg < 4; reg++) {
        const int row = bm + wm * 64 + mi * 16 + quad * 4 + reg;
        const int col = bn + wn * 64 + ni * 16 + m16;
        if (OUT_BF16)
          ((__hip_bfloat16*)Cout)[(size_t)row * N + col] = __float2bfloat16(acc[mi][ni][reg]);
        else
          ((float*)Cout)[(size_t)row * N + col] = acc[mi][ni][reg];
      }
}

// =====================================================================
// RoPE on bf16 (interleaved pairs) + scale; strided rows (fused qkv)
// =====================================================================
__global__ __launch_bounds__(256) void rope_bf16(__hip_bfloat16* __restrict__ base,
                                                 int rowStride,
                                                 const float* __restrict__ cosT,
                                                 const float* __restrict__ sinT,
                                                 const float* __restrict__ temp,
                                                 int nheads, float extra, int use_temp) {
  const int unit = blockIdx.x * 4 + (threadIdx.x >> 6);
  const int lane = threadIdx.x & 63;
  const int h = unit % nheads;
  const int bt = unit / nheads;
  const int t = bt & (T_ - 1);
  const float scale = extra * (use_temp ? temp[h] : 1.0f);
  __hip_bfloat16* p = base + (size_t)bt * rowStride + h * DH_;
  if (lane < 32) {
    const float x1 = __bfloat162float(p[2 * lane]);
    const float x2 = __bfloat162float(p[2 * lane + 1]);
    const float c = cosT[t * (RD_ / 2) + lane];
    const float s = sinT[t * (RD_ / 2) + lane];
    p[2 * lane]     = __float2bfloat16((x1 * c - x2 * s) * scale);
    p[2 * lane + 1] = __float2bfloat16((x1 * s + x2 * c) * scale);
  } else {
    const int d0 = RD_ + (lane - 32) * 2;
    p[d0]     = __float2bfloat16(__bfloat162float(p[d0]) * scale);
    p[d0 + 1] = __float2bfloat16(__bfloat162float(p[d0 + 1]) * scale);
  }
}

// =====================================================================
// V transpose: v-part of qkv (row stride SQKV) -> vt (B, HKV, DH, T)
// =====================================================================
__global__ __launch_bounds__(256) void transpose_v(const __hip_bfloat16* __restrict__ v,
                                                   __hip_bfloat16* __restrict__ vt) {
  __shared__ __hip_bfloat16 Ts[64][72];
  const int t0 = blockIdx.x * 64, d0 = blockIdx.y * 64;
  const int bh = blockIdx.z;
  const int b = bh >> 2, hv = bh & 3;
  const int tid = threadIdx.x;
  const int r = tid >> 2, c0 = (tid & 3) * 16;

  const __hip_bfloat16* src = v + ((size_t)(b * T_) + t0 + r) * SQKV + hv * DH_ + d0 + c0;
  *(short8*)&Ts[r][c0]     = *(const short8*)(src);
  *(short8*)&Ts[r][c0 + 8] = *(const short8*)(src + 8);
  __syncthreads();

  union { short8 v8[2]; __hip_bfloat16 h[16]; } tmp;
#pragma unroll
  for (int j = 0; j < 16; j++) tmp.h[j] = Ts[c0 + j][r];
  __hip_bfloat16* dst = vt + ((size_t)((b * HKV_ + hv) * DH_) + d0 + r) * T_ + t0 + c0;
  *(short8*)dst       = tmp.v8[0];
  *(short8*)(dst + 8) = tmp.v8[1];
}

// =====================================================================
// MFMA flash attention, double-buffered K/V staging, P overlaid in the
// retired K buffer. LDS = exactly 64 KB -> 2 blocks/CU.
// Heavy-first: qt = 31 - (bid & 31).
// =====================================================================
__global__ __launch_bounds__(256) void flash_attn_mfma(
    const __hip_bfloat16* __restrict__ qkv,  // [B*T][SQKV] (q | k | v)
    const __hip_bfloat16* __restrict__ vt,   // [B][HKV][DH][T]
    __hip_bfloat16* __restrict__ ao) {       // [B*T][D]
  __shared__ __hip_bfloat16 smem[32768];     // 64 KB
  __hip_bfloat16* const Kb0 = smem;
  __hip_bfloat16* const Kb1 = smem + 8192;
  __hip_bfloat16* const Vb0 = smem + 16384;
  __hip_bfloat16* const Vb1 = smem + 24576;

  const int tid = threadIdx.x, lane = tid & 63, w = tid >> 6;
  const int quad = lane >> 4, m16 = lane & 15;
  const int bid = blockIdx.x;
  const int qt = 31 - (bid & 31);            // heavy tiles dispatch first
  const int bh = bid >> 5;
  const int h = bh & 15;
  const int b = bh >> 4;
  const int kvh = h >> 2;
  const int qg = qt * 64;

  // Q fragments in registers (4 dh-steps of 32)
  short8 qa[4];
  {
    const __hip_bfloat16* qp = qkv + ((size_t)(b * T_) + qg + w * 16 + m16) * SQKV + h * DH_;
#pragma unroll
    for (int ks = 0; ks < 4; ks++) qa[ks] = *(const short8*)(qp + ks * 32 + quad * 8);
  }

  // per-lane staging base pointers (advanced by one slab each iter)
  const int subq = lane >> 4;
  const int rlow = lane & 15;
  const __hip_bfloat16* kptr[4];
  const __hip_bfloat16* vptr[4];
#pragma unroll
  for (int e = 0; e < 4; e++) {
    const int I = w * 4 + e;
    const int panelK = I >> 2, kcK = (I & 3) * 4 + subq;
    kptr[e] = qkv + D_ + ((size_t)(b * T_) + panelK * 16 + rlow) * SQKV + kvh * DH_ + kcK * 8;
    const int panelV = I >> 1, tc = (I & 1) * 4 + subq;
    vptr[e] = vt + ((size_t)((b * HKV_ + kvh) * DH_) + panelV * 16 + rlow) * T_ + tc * 8;
  }

  // prologue: stage slab 0 into buffer 0
#pragma unroll
  for (int e = 0; e < 4; e++) {
    const int I = w * 4 + e;
    async16(kptr[e], Kb0 + I * 512);
    async16(vptr[e], Vb0 + I * 512);
    kptr[e] += (size_t)64 * SQKV;
    vptr[e] += 64;
  }

  floatx4 o_acc[8] = {};
  float m_i[4], l_i[4];
#pragma unroll
  for (int r = 0; r < 4; r++) { m_i[r] = -1e30f; l_i[r] = 0.0f; }

  for (int kt = 0; kt <= qt; kt++) {
    __hip_bfloat16* const Kc = (kt & 1) ? Kb1 : Kb0;
    __hip_bfloat16* const Vc = (kt & 1) ? Vb1 : Vb0;
    __hip_bfloat16* const Kn = (kt & 1) ? Kb0 : Kb1;
    __hip_bfloat16* const Vn = (kt & 1) ? Vb0 : Vb1;

    // barrier A: prev compute done (safe to overwrite Kn/Vn); drains slab-kt loads
    __syncthreads();

    if (kt < qt) {  // prefetch slab kt+1
#pragma unroll
      for (int e = 0; e < 4; e++) {
        const int I = w * 4 + e;
        async16(kptr[e], Kn + I * 512);
        async16(vptr[e], Vn + I * 512);
        kptr[e] += (size_t)64 * SQKV;
        vptr[e] += 64;
      }
    }

    // ---- S = Q K^T (16 q-rows x 64 k-cols per wave) ----
    floatx4 sacc[4] = {};
#pragma unroll
    for (int ni = 0; ni < 4; ni++)
#pragma unroll
      for (int ks = 0; ks < 4; ks++) {
        const int unit = ni * 256 + (ks * 4 + quad) * 16 + m16;
        const short8 kb = *(const short8*)&Kc[unit * 8];
        sacc[ni] = __builtin_amdgcn_mfma_f32_16x16x32_bf16(qa[ks], kb, sacc[ni], 0, 0, 0);
      }

    if (kt == qt) {  // causal mask on diagonal slab
#pragma unroll
      for (int ni = 0; ni < 4; ni++) {
        const int colg = kt * 64 + ni * 16 + m16;
#pragma unroll
        for (int reg = 0; reg < 4; reg++) {
          const int rowg = qg + w * 16 + quad * 4 + reg;
          if (colg > rowg) sacc[ni][reg] = -1e30f;
        }
      }
    }

    // ---- online softmax (rows wave-private; reduce over 16 lanes) ----
    float alpha[4];
#pragma unroll
    for (int reg = 0; reg < 4; reg++) {
      float v = fmaxf(fmaxf(sacc[0][reg], sacc[1][reg]), fmaxf(sacc[2][reg], sacc[3][reg]));
      v = fmaxf(v, __shfl_xor(v, 1));
      v = fmaxf(v, __shfl_xor(v, 2));
      v = fmaxf(v, __shfl_xor(v, 4));
      v = fmaxf(v, __shfl_xor(v, 8));
      const float mn = fmaxf(m_i[reg], v);
      alpha[reg] = __expf(m_i[reg] - mn);
      m_i[reg] = mn;
    }
#pragma unroll
    for (int ni = 0; ni < 4; ni++)
#pragma unroll
      for (int reg = 0; reg < 4; reg++)
        sacc[ni][reg] = __expf(sacc[ni][reg] - m_i[reg]);
#pragma unroll
    for (int reg = 0; reg < 4; reg++) {
      float s = sacc[0][reg] + sacc[1][reg] + sacc[2][reg] + sacc[3][reg];
      s += __shfl_xor(s, 1);
      s += __shfl_xor(s, 2);
      s += __shfl_xor(s, 4);
      s += __shfl_xor(s, 8);
      l_i[reg] = l_i[reg] * alpha[reg] + s;
    }
    // rescale O while waiting at barrier B
#pragma unroll
    for (int ni = 0; ni < 8; ni++)
#pragma unroll
      for (int reg = 0; reg < 4; reg++) o_acc[ni][reg] *= alpha[reg];

    // barrier B: all waves' QK reads of Kc done -> safe to overlay P in Kc
    __syncthreads();

    __hip_bfloat16* const Pw = Kc + w * 1152;  // per-wave 16x72 region
#pragma unroll
    for (int ni = 0; ni < 4; ni++)
#pragma unroll
      for (int reg = 0; reg < 4; reg++)
        Pw[(quad * 4 + reg) * 72 + ni * 16 + m16] = __float2bfloat16(sacc[ni][reg]);

    // ---- O += P V ----
#pragma unroll
    for (int ks2 = 0; ks2 < 2; ks2++) {
      const short8 pa = *(const short8*)&Pw[m16 * 72 + ks2 * 32 + quad * 8];
#pragma unroll
      for (int ni = 0; ni < 8; ni++) {
        const int unit = ni * 128 + (ks2 * 4 + quad) * 16 + m16;
        const short8 vb = *(const short8*)&Vc[unit * 8];
        o_acc[ni] = __builtin_amdgcn_mfma_f32_16x16x32_bf16(pa, vb, o_acc[ni], 0, 0, 0);
      }
    }
  }

  // ---- epilogue ----
  const size_t orow = (size_t)(b * T_) + qg + w * 16;
#pragma unroll
  for (int reg = 0; reg < 4; reg++) {
    const float inv = 1.0f / l_i[reg];
#pragma unroll
    for (int ni = 0; ni < 8; ni++)
      ao[(orow + quad * 4 + reg) * D_ + h * DH_ + ni * 16 + m16] =
          __float2bfloat16(o_acc[ni][reg] * inv);
  }
}

// =====================================================================
// Launch
// =====================================================================
extern "C" void kernel_launch(void* const* d_in, const int* in_sizes, int n_in,
                              void* d_out, int out_size, void* d_ws, size_t ws_size,
                              hipStream_t stream) {
  const float* x    = (const float*)d_in[0];
  const float* cosT = (const float*)d_in[1];
  const float* sinT = (const float*)d_in[2];
  const float* Wq   = (const float*)d_in[3];
  const float* Wk   = (const float*)d_in[4];
  const float* Wv   = (const float*)d_in[5];
  const float* Wo   = (const float*)d_in[6];
  const float* temp = (const float*)d_in[7];
  float* out = (float*)d_out;

  const int M = B_ * T_;                     // 4096
  const size_t XN   = (size_t)M * D_;        // 8388608
  const size_t WQN  = (size_t)D_ * D_;       // 4194304
  const size_t WKN  = (size_t)KD_ * D_;      // 1048576
  const size_t QKVN = (size_t)M * SQKV;      // 12582912
  const size_t KN   = (size_t)M * KD_;       // 2097152

  __hip_bfloat16* ws = (__hip_bfloat16*)d_ws;
  __hip_bfloat16* xb    = ws;  ws += XN;
  __hip_bfloat16* wqkvb = ws;  ws += WQN + 2 * WKN;  // Wq|Wk|Wv rows contiguous: [3072][2048]
  __hip_bfloat16* wob   = ws;  ws += WQN;
  __hip_bfloat16* qkvb  = ws;  ws += QKVN;           // [4096][3072]
  __hip_bfloat16* vtb   = ws;  ws += KN;
  __hip_bfloat16* aob   = ws;  ws += XN;

  dim3 blk(256);

  // 1. convert inputs to bf16 (Wq/Wk/Wv land contiguously -> fused weight)
  ConvArgs ca;
  ca.src[0] = x;  ca.dst[0] = xb;                  ca.n[0] = (int)XN;
  ca.src[1] = Wq; ca.dst[1] = wqkvb;               ca.n[1] = (int)WQN;
  ca.src[2] = Wk; ca.dst[2] = wqkvb + WQN;         ca.n[2] = (int)WKN;
  ca.src[3] = Wv; ca.dst[3] = wqkvb + WQN + WKN;   ca.n[3] = (int)WKN;
  ca.src[4] = Wo; ca.dst[4] = wob;                 ca.n[4] = (int)WQN;
  conv_bf16<<<dim3(4096, 5), blk, 0, stream>>>(ca);

  // 2. fused QKV projection: [4096][3072]
  gemm_bt_mfma<1><<<dim3(SQKV / 128, M / 128), blk, 0, stream>>>(xb, wqkvb, qkvb, M, SQKV, D_);

  // 3. rope (+ temp & 1/sqrt(DH) folded into q)
  const float inv_sqrt_dh = 1.0f / sqrtf((float)DH_);
  rope_bf16<<<(M * H_) / 4, blk, 0, stream>>>(qkvb, SQKV, cosT, sinT, temp, H_, inv_sqrt_dh, 1);
  rope_bf16<<<(M * HKV_) / 4, blk, 0, stream>>>(qkvb + D_, SQKV, cosT, sinT, temp, HKV_, 1.0f, 0);

  // 4. transpose V for PV b-fragments
  transpose_v<<<dim3(T_ / 64, DH_ / 64, B_ * HKV_), blk, 0, stream>>>(qkvb + D_ + KD_, vtb);

  // 5. attention
  flash_attn_mfma<<<B_ * H_ * (T_ / 64), blk, 0, stream>>>(qkvb, vtb, aob);

  // 6. output projection (fp32 out)
  gemm_bt_mfma<0><<<dim3(D_ / 128, M / 128), blk, 0, stream>>>(aob, wob, out, M, D_, D_);
}